// Round 1
// baseline (350.642 us; speedup 1.0000x reference)
//
#include <hip/hip_runtime.h>

typedef __bf16 bf16;
typedef __attribute__((ext_vector_type(8))) bf16 bf16x8;
typedef __attribute__((ext_vector_type(4))) bf16 bf16x4;
typedef __attribute__((ext_vector_type(4))) float f32x4;

#define MFMA16(a, b, c) __builtin_amdgcn_mfma_f32_16x16x32_bf16(a, b, c, 0, 0, 0)

constexpr int Bb = 4, Ss = 4096, Ee = 1024, Hh = 128;
constexpr int Mrows = Bb * Ss;  // 16384

// ---------------------------------------------------------------------------
// Kernel 1: QKV projection.  [16384,1024]f32 @ [1024,128]f32 + bias -> bf16
// grid (Mrows/64, 3), block 256 (4 waves). which: 0=Q (pre-scaled 1/sqrt(H)),
// 1=K, 2=V.
// ---------------------------------------------------------------------------
__global__ __launch_bounds__(256) void proj_kernel(
    const float* __restrict__ embds,
    const float* __restrict__ Wq, const float* __restrict__ bq,
    const float* __restrict__ Wk, const float* __restrict__ bk,
    const float* __restrict__ Wv, const float* __restrict__ bv,
    bf16* __restrict__ Qb, bf16* __restrict__ Kb, bf16* __restrict__ Vb)
{
    const int which = blockIdx.y;
    const float* W; const float* bias; bf16* dst; float scale;
    if (which == 0)      { W = Wq; bias = bq; dst = Qb; scale = 0.08838834764831843f; }
    else if (which == 1) { W = Wk; bias = bk; dst = Kb; scale = 1.0f; }
    else                 { W = Wv; bias = bv; dst = Vb; scale = 1.0f; }

    // As: 64 rows x 64 k (pad to 72 -> 144B row stride, 16B aligned, 4-bank step)
    __shared__ bf16 As[64][72];
    // Bs: W tile stored TRANSPOSED: Bs[n][k] so B-fragments are contiguous b128
    __shared__ bf16 Bs[128][72];

    const int t = threadIdx.x;
    const int wv = t >> 6, lane = t & 63, lo = lane & 15, hi = lane >> 4;
    const int m0 = blockIdx.x * 64;

    f32x4 acc[8];
    #pragma unroll
    for (int f = 0; f < 8; ++f) acc[f] = f32x4{0.f, 0.f, 0.f, 0.f};

    const int arow = t >> 2, acg = (t & 3) * 16;

    for (int k0 = 0; k0 < Ee; k0 += 64) {
        // stage A: 64x64 f32 -> bf16 (each thread: 16 contiguous floats)
        {
            const float4* src = reinterpret_cast<const float4*>(
                embds + (size_t)(m0 + arow) * Ee + k0 + acg);
            #pragma unroll
            for (int j = 0; j < 4; ++j) {
                float4 v = src[j];
                As[arow][acg + j*4 + 0] = (bf16)v.x;
                As[arow][acg + j*4 + 1] = (bf16)v.y;
                As[arow][acg + j*4 + 2] = (bf16)v.z;
                As[arow][acg + j*4 + 3] = (bf16)v.w;
            }
        }
        // stage B transposed: 64k x 128n, coalesced read along n
        #pragma unroll
        for (int rep = 0; rep < 8; ++rep) {
            int idx4 = rep * 256 + t;
            int kr = idx4 >> 5, n4 = idx4 & 31;
            float4 v = *reinterpret_cast<const float4*>(W + (size_t)(k0 + kr) * Hh + n4 * 4);
            Bs[n4*4 + 0][kr] = (bf16)v.x;
            Bs[n4*4 + 1][kr] = (bf16)v.y;
            Bs[n4*4 + 2][kr] = (bf16)v.z;
            Bs[n4*4 + 3][kr] = (bf16)v.w;
        }
        __syncthreads();
        #pragma unroll
        for (int kk = 0; kk < 2; ++kk) {
            bf16x8 a = *reinterpret_cast<const bf16x8*>(&As[wv*16 + lo][kk*32 + hi*8]);
            #pragma unroll
            for (int f = 0; f < 8; ++f) {
                bf16x8 b = *reinterpret_cast<const bf16x8*>(&Bs[f*16 + lo][kk*32 + hi*8]);
                acc[f] = MFMA16(a, b, acc[f]);
            }
        }
        __syncthreads();
    }
    // epilogue: + bias, * scale, cast bf16
    #pragma unroll
    for (int f = 0; f < 8; ++f) {
        int col = f*16 + lo;
        float bv_ = bias[col];
        #pragma unroll
        for (int i = 0; i < 4; ++i) {
            int row = m0 + wv*16 + hi*4 + i;
            float v = (acc[f][i] + bv_) * scale;
            dst[(size_t)row * Hh + col] = (bf16)v;
        }
    }
}

// ---------------------------------------------------------------------------
// Kernel 2: causal flash attention. grid (S/64, B), block 256 (4 waves).
// Each wave owns 16 q-rows; block iterates KV tiles of 64.
// ---------------------------------------------------------------------------
__global__ __launch_bounds__(256) void attn_kernel(
    const bf16* __restrict__ Qb, const bf16* __restrict__ Kb,
    const bf16* __restrict__ Vb, float* __restrict__ out)
{
    __shared__ bf16 Ks[64][136];   // K tile row-major, 272B stride (16B-aligned)
    __shared__ bf16 Vt[128][72];   // V tile transposed: Vt[h][kv]
    __shared__ bf16 Ps[4][16][72]; // per-wave P round-trip

    const int t = threadIdx.x;
    const int wv = t >> 6, lane = t & 63, lo = lane & 15, hi = lane >> 4;
    const int qb = blockIdx.x, b = blockIdx.y;
    const int q0 = qb * 64;
    const size_t base = (size_t)b * Ss * Hh;

    // Q fragments hoisted to registers (pre-scaled by 1/sqrt(H) in proj)
    bf16x8 qf[4];
    #pragma unroll
    for (int kk = 0; kk < 4; ++kk)
        qf[kk] = *reinterpret_cast<const bf16x8*>(
            Qb + base + (size_t)(q0 + wv*16 + lo) * Hh + kk*32 + hi*8);

    f32x4 acc[8];
    #pragma unroll
    for (int f = 0; f < 8; ++f) acc[f] = f32x4{0.f, 0.f, 0.f, 0.f};
    float M_[4] = {-INFINITY, -INFINITY, -INFINITY, -INFINITY};
    float L_[4] = {0.f, 0.f, 0.f, 0.f};

    const int ntiles = qb + 1;
    for (int tile = 0; tile < ntiles; ++tile) {
        const int kv0 = tile * 64;
        // stage K: 64x128 bf16, 16B chunks, fully coalesced
        #pragma unroll
        for (int rep = 0; rep < 4; ++rep) {
            int c = rep * 256 + t;
            int r = c >> 4, c8 = c & 15;
            *reinterpret_cast<uint4*>(&Ks[r][c8*8]) =
                *reinterpret_cast<const uint4*>(Kb + base + (size_t)(kv0 + r) * Hh + c8*8);
        }
        // stage V transposed (coalesced 8B reads, scattered LDS writes)
        #pragma unroll
        for (int rep = 0; rep < 8; ++rep) {
            int idx4 = rep * 256 + t;
            int r = idx4 >> 5, h4 = idx4 & 31;
            bf16x4 v = *reinterpret_cast<const bf16x4*>(
                Vb + base + (size_t)(kv0 + r) * Hh + h4*4);
            Vt[h4*4 + 0][r] = v[0];
            Vt[h4*4 + 1][r] = v[1];
            Vt[h4*4 + 2][r] = v[2];
            Vt[h4*4 + 3][r] = v[3];
        }
        __syncthreads();

        // S = Q K^T  (4 col-frags x 4 k-steps over H=128)
        f32x4 sv[4];
        #pragma unroll
        for (int f = 0; f < 4; ++f) sv[f] = f32x4{0.f, 0.f, 0.f, 0.f};
        #pragma unroll
        for (int kk = 0; kk < 4; ++kk) {
            #pragma unroll
            for (int f = 0; f < 4; ++f) {
                bf16x8 kf = *reinterpret_cast<const bf16x8*>(&Ks[f*16 + lo][kk*32 + hi*8]);
                sv[f] = MFMA16(qf[kk], kf, sv[f]);
            }
        }
        // causal mask (only the diagonal tile needs it)
        if (kv0 == q0) {
            #pragma unroll
            for (int f = 0; f < 4; ++f) {
                int c = f*16 + lo;
                #pragma unroll
                for (int i = 0; i < 4; ++i) {
                    int r = wv*16 + hi*4 + i;
                    if (c > r) sv[f][i] = -INFINITY;
                }
            }
        }
        // online softmax per owned row i (rows = wv*16 + hi*4 + i)
        #pragma unroll
        for (int i = 0; i < 4; ++i) {
            float pm = fmaxf(fmaxf(sv[0][i], sv[1][i]), fmaxf(sv[2][i], sv[3][i]));
            #pragma unroll
            for (int m = 1; m < 16; m <<= 1) pm = fmaxf(pm, __shfl_xor(pm, m));
            float nM = fmaxf(M_[i], pm);
            float sc = __expf(M_[i] - nM);
            float rs = 0.f;
            #pragma unroll
            for (int f = 0; f < 4; ++f) {
                float e0 = __expf(sv[f][i] - nM);
                sv[f][i] = e0;
                rs += e0;
            }
            #pragma unroll
            for (int m = 1; m < 16; m <<= 1) rs += __shfl_xor(rs, m);
            L_[i] = L_[i] * sc + rs;
            M_[i] = nM;
            #pragma unroll
            for (int f = 0; f < 8; ++f) acc[f][i] *= sc;
        }
        // P -> LDS (re-layout for PV A-operand)
        #pragma unroll
        for (int f = 0; f < 4; ++f) {
            #pragma unroll
            for (int i = 0; i < 4; ++i)
                Ps[wv][hi*4 + i][f*16 + lo] = (bf16)sv[f][i];
        }
        __syncthreads();
        // O += P V  (8 h-frags x 2 k-steps over KV=64)
        #pragma unroll
        for (int kk = 0; kk < 2; ++kk) {
            bf16x8 pa = *reinterpret_cast<const bf16x8*>(&Ps[wv][lo][kk*32 + hi*8]);
            #pragma unroll
            for (int f = 0; f < 8; ++f) {
                bf16x8 vf = *reinterpret_cast<const bf16x8*>(&Vt[f*16 + lo][kk*32 + hi*8]);
                acc[f] = MFMA16(pa, vf, acc[f]);
            }
        }
        __syncthreads();
    }
    // epilogue: normalize by L, store f32
    #pragma unroll
    for (int f = 0; f < 8; ++f) {
        #pragma unroll
        for (int i = 0; i < 4; ++i) {
            int row = q0 + wv*16 + hi*4 + i;
            out[base + (size_t)row * Hh + f*16 + lo] = acc[f][i] / L_[i];
        }
    }
}

extern "C" void kernel_launch(void* const* d_in, const int* in_sizes, int n_in,
                              void* d_out, int out_size, void* d_ws, size_t ws_size,
                              hipStream_t stream) {
    const float* embds = (const float*)d_in[0];
    const float* Wq = (const float*)d_in[1];
    const float* bq = (const float*)d_in[2];
    const float* Wk = (const float*)d_in[3];
    const float* bk = (const float*)d_in[4];
    const float* Wv = (const float*)d_in[5];
    const float* bv = (const float*)d_in[6];
    float* out = (float*)d_out;

    bf16* Qb = (bf16*)d_ws;                       // 16384*128 bf16 = 4 MB
    bf16* Kb = Qb + (size_t)Mrows * Hh;
    bf16* Vb = Kb + (size_t)Mrows * Hh;           // total 12 MB of d_ws

    proj_kernel<<<dim3(Mrows / 64, 3), 256, 0, stream>>>(
        embds, Wq, bq, Wk, bk, Wv, bv, Qb, Kb, Vb);
    attn_kernel<<<dim3(Ss / 64, Bb), 256, 0, stream>>>(Qb, Kb, Vb, out);
}

// Round 2
// 153.129 us; speedup vs baseline: 2.2899x; 2.2899x over previous
//
#include <hip/hip_runtime.h>

typedef __bf16 bf16;
typedef __attribute__((ext_vector_type(2))) bf16 bf16x2;
typedef __attribute__((ext_vector_type(4))) bf16 bf16x4;
typedef __attribute__((ext_vector_type(8))) bf16 bf16x8;
typedef __attribute__((ext_vector_type(4))) float f32x4;

#define MFMA16(a, b, c) __builtin_amdgcn_mfma_f32_16x16x32_bf16(a, b, c, 0, 0, 0)

constexpr int Bb = 4, Ss = 4096, Ee = 1024, Hh = 128;
constexpr int Mrows = Bb * Ss;  // 16384

// ---------------------------------------------------------------------------
// Kernel 0: one-time W prep. Transpose W [E,H] f32 -> Wt [3][H][E] bf16,
// convert biases. grid (E/64, 3), block 256.
// ---------------------------------------------------------------------------
__global__ __launch_bounds__(256) void wprep_kernel(
    const float* __restrict__ Wq, const float* __restrict__ Wk,
    const float* __restrict__ Wv,
    const float* __restrict__ bq, const float* __restrict__ bk,
    const float* __restrict__ bv,
    bf16* __restrict__ Wt, bf16* __restrict__ Biasb)
{
    __shared__ bf16 Sb[64][132];
    const int w = blockIdx.y;
    const float* W = (w == 0) ? Wq : (w == 1) ? Wk : Wv;
    const int k0 = blockIdx.x * 64;
    const int t = threadIdx.x;
    {
        int r = t >> 2, cg = (t & 3) * 32;
        const float4* src = (const float4*)(W + (size_t)(k0 + r) * Hh + cg);
        #pragma unroll
        for (int j = 0; j < 8; ++j) {
            float4 v = src[j];
            bf16x4 o; o[0] = (bf16)v.x; o[1] = (bf16)v.y; o[2] = (bf16)v.z; o[3] = (bf16)v.w;
            *(bf16x4*)&Sb[r][cg + j * 4] = o;
        }
    }
    __syncthreads();
    {
        int h = t >> 1, kseg = (t & 1) * 32;
        #pragma unroll
        for (int c = 0; c < 4; ++c) {
            bf16x8 v;
            #pragma unroll
            for (int e = 0; e < 8; ++e) v[e] = Sb[kseg + c * 8 + e][h];
            *(bf16x8*)&Wt[((size_t)w * Hh + h) * Ee + k0 + kseg + c * 8] = v;
        }
    }
    if (blockIdx.x == 0 && t < Hh) {
        const float* bias = (w == 0) ? bq : (w == 1) ? bk : bv;
        Biasb[w * Hh + t] = (bf16)bias[t];
    }
}

// ---------------------------------------------------------------------------
// Kernel 1: fused QKV projection. Each block: 64 rows x (3 x 128) outputs.
// A staged once per k-iter and reused for Q,K,V. grid (Mrows/64), block 256.
// ---------------------------------------------------------------------------
__global__ __launch_bounds__(256) void proj_kernel(
    const float* __restrict__ embds, const bf16* __restrict__ Wt,
    const bf16* __restrict__ Biasb,
    bf16* __restrict__ Qb, bf16* __restrict__ Kb, bf16* __restrict__ Vb)
{
    __shared__ bf16 As[64][72];
    __shared__ bf16 Bs[3][128][72];

    const int t = threadIdx.x;
    const int wv = t >> 6, lane = t & 63, lo = lane & 15, hi = lane >> 4;
    const int m0 = blockIdx.x * 64;

    f32x4 acc[3][8];
    #pragma unroll
    for (int w = 0; w < 3; ++w)
        #pragma unroll
        for (int f = 0; f < 8; ++f) acc[w][f] = f32x4{0.f, 0.f, 0.f, 0.f};

    const int arow = t >> 2, acg = (t & 3) * 16;

    for (int k0 = 0; k0 < Ee; k0 += 64) {
        // stage A: 64x64 f32 -> bf16, vectorized 8B stores
        {
            const float4* src = (const float4*)(embds + (size_t)(m0 + arow) * Ee + k0 + acg);
            #pragma unroll
            for (int j = 0; j < 4; ++j) {
                float4 v = src[j];
                bf16x4 o; o[0] = (bf16)v.x; o[1] = (bf16)v.y; o[2] = (bf16)v.z; o[3] = (bf16)v.w;
                *(bf16x4*)&As[arow][acg + j * 4] = o;
            }
        }
        // stage B: 3 x 128 rows x 64 k, pure uint4 copies from bf16 Wt
        #pragma unroll
        for (int rep = 0; rep < 12; ++rep) {
            int idx = rep * 256 + t;             // 0..3071
            int w = idx >> 10, row = (idx >> 3) & 127, c = idx & 7;
            *(uint4*)&Bs[w][row][c * 8] =
                *(const uint4*)&Wt[((size_t)w * Hh + row) * Ee + k0 + c * 8];
        }
        __syncthreads();
        #pragma unroll
        for (int kk = 0; kk < 2; ++kk) {
            bf16x8 a = *(const bf16x8*)&As[wv * 16 + lo][kk * 32 + hi * 8];
            #pragma unroll
            for (int w = 0; w < 3; ++w)
                #pragma unroll
                for (int f = 0; f < 8; ++f) {
                    bf16x8 b = *(const bf16x8*)&Bs[w][f * 16 + lo][kk * 32 + hi * 8];
                    acc[w][f] = MFMA16(a, b, acc[w][f]);
                }
        }
        __syncthreads();
    }
    #pragma unroll
    for (int w = 0; w < 3; ++w) {
        bf16* dst = (w == 0) ? Qb : (w == 1) ? Kb : Vb;
        float scale = (w == 0) ? 0.08838834764831843f : 1.0f;
        #pragma unroll
        for (int f = 0; f < 8; ++f) {
            int col = f * 16 + lo;
            float bvv = (float)Biasb[w * Hh + col];
            #pragma unroll
            for (int i = 0; i < 4; ++i) {
                int row = m0 + wv * 16 + hi * 4 + i;
                dst[(size_t)row * Hh + col] = (bf16)((acc[w][f][i] + bvv) * scale);
            }
        }
    }
}

// ---------------------------------------------------------------------------
// Kernel 2: split-KV causal flash attention. grid (S/64, B, NC), block 256.
// Block (qb,b,c) covers KV tiles [c*C, min((c+1)*C, qb+1)); writes
// unnormalized partial O + per-row (M,L) to workspace.
// ---------------------------------------------------------------------------
__global__ __launch_bounds__(256) void attn_kernel(
    const bf16* __restrict__ Qb, const bf16* __restrict__ Kb,
    const bf16* __restrict__ Vb,
    float* __restrict__ Opart, float* __restrict__ Mpart, float* __restrict__ Lpart,
    int NC, int C)
{
    __shared__ bf16 Ks[64][136];   // K tile row-major, 272B stride
    __shared__ bf16 Vt[128][64];   // V transposed, XOR-swizzled columns
    __shared__ bf16 Ps[4][16][72]; // per-wave P re-layout (wave-private)

    const int t = threadIdx.x;
    const int wv = t >> 6, lane = t & 63, lo = lane & 15, hi = lane >> 4;
    const int qb = blockIdx.x, b = blockIdx.y, c = blockIdx.z;
    if (c * C > qb) return;                       // empty chunk
    const int tend = min((c + 1) * C, qb + 1);
    const int q0 = qb * 64;
    const size_t base = (size_t)b * Ss * Hh;

    bf16x8 qf[4];
    #pragma unroll
    for (int kk = 0; kk < 4; ++kk)
        qf[kk] = *(const bf16x8*)(Qb + base + (size_t)(q0 + wv * 16 + lo) * Hh + kk * 32 + hi * 8);

    f32x4 acc[8];
    #pragma unroll
    for (int f = 0; f < 8; ++f) acc[f] = f32x4{0.f, 0.f, 0.f, 0.f};
    float M_[4] = {-INFINITY, -INFINITY, -INFINITY, -INFINITY};
    float L_[4] = {0.f, 0.f, 0.f, 0.f};

    const int swzr = (lo >> 2) << 3;              // V read-side swizzle

    for (int tile = c * C; tile < tend; ++tile) {
        const int kv0 = tile * 64;
        // stage K: uint4 copies
        #pragma unroll
        for (int rep = 0; rep < 4; ++rep) {
            int ci = rep * 256 + t;
            int r = ci >> 4, c8 = ci & 15;
            *(uint4*)&Ks[r][c8 * 8] =
                *(const uint4*)(Kb + base + (size_t)(kv0 + r) * Hh + c8 * 8);
        }
        // stage V transposed: paired rows -> bf16x2 stores, swizzled cols
        #pragma unroll
        for (int rep = 0; rep < 4; ++rep) {
            int idx = rep * 256 + t;              // 0..1023
            int rp = idx >> 5, h4 = idx & 31;
            const bf16* vsrc = Vb + base + (size_t)(kv0 + 2 * rp) * Hh + h4 * 4;
            bf16x4 a = *(const bf16x4*)vsrc;
            bf16x4 b2 = *(const bf16x4*)(vsrc + Hh);
            int col = (2 * rp) ^ ((h4 & 3) << 3);
            #pragma unroll
            for (int j = 0; j < 4; ++j) {
                bf16x2 p; p[0] = a[j]; p[1] = b2[j];
                *(bf16x2*)&Vt[h4 * 4 + j][col] = p;
            }
        }
        __syncthreads();

        // S = Q K^T
        f32x4 sv[4];
        #pragma unroll
        for (int f = 0; f < 4; ++f) sv[f] = f32x4{0.f, 0.f, 0.f, 0.f};
        #pragma unroll
        for (int kk = 0; kk < 4; ++kk) {
            #pragma unroll
            for (int f = 0; f < 4; ++f) {
                bf16x8 kf = *(const bf16x8*)&Ks[f * 16 + lo][kk * 32 + hi * 8];
                sv[f] = MFMA16(qf[kk], kf, sv[f]);
            }
        }
        if (kv0 == q0) {   // diagonal tile mask
            #pragma unroll
            for (int f = 0; f < 4; ++f) {
                int cc = f * 16 + lo;
                #pragma unroll
                for (int i = 0; i < 4; ++i) {
                    int r = wv * 16 + hi * 4 + i;
                    if (cc > r) sv[f][i] = -INFINITY;
                }
            }
        }
        // online softmax (rows owned: wv*16 + hi*4 + i)
        #pragma unroll
        for (int i = 0; i < 4; ++i) {
            float pm = fmaxf(fmaxf(sv[0][i], sv[1][i]), fmaxf(sv[2][i], sv[3][i]));
            #pragma unroll
            for (int m = 1; m < 16; m <<= 1) pm = fmaxf(pm, __shfl_xor(pm, m));
            float nM = fmaxf(M_[i], pm);
            float sc = __expf(M_[i] - nM);
            float rs = 0.f;
            #pragma unroll
            for (int f = 0; f < 4; ++f) {
                float e0 = __expf(sv[f][i] - nM);
                sv[f][i] = e0;
                rs += e0;
            }
            #pragma unroll
            for (int m = 1; m < 16; m <<= 1) rs += __shfl_xor(rs, m);
            L_[i] = L_[i] * sc + rs;
            M_[i] = nM;
            #pragma unroll
            for (int f = 0; f < 8; ++f) acc[f][i] *= sc;
        }
        // P -> LDS (wave-private, no barrier needed)
        #pragma unroll
        for (int f = 0; f < 4; ++f)
            #pragma unroll
            for (int i = 0; i < 4; ++i)
                Ps[wv][hi * 4 + i][f * 16 + lo] = (bf16)sv[f][i];
        // O += P V
        #pragma unroll
        for (int kk = 0; kk < 2; ++kk) {
            bf16x8 pa = *(const bf16x8*)&Ps[wv][lo][kk * 32 + hi * 8];
            #pragma unroll
            for (int f = 0; f < 8; ++f) {
                bf16x8 vf = *(const bf16x8*)&Vt[f * 16 + lo][(kk * 32 + hi * 8) ^ swzr];
                acc[f] = MFMA16(pa, vf, acc[f]);
            }
        }
        __syncthreads();
    }
    // write partials (unnormalized O, M, L)
    const size_t pb = (((size_t)b * 64 + qb) * NC + c) * 64;
    #pragma unroll
    for (int f = 0; f < 8; ++f)
        #pragma unroll
        for (int i = 0; i < 4; ++i) {
            int row = wv * 16 + hi * 4 + i;
            Opart[(pb + row) * 128 + f * 16 + lo] = acc[f][i];
        }
    if (lo == 0) {
        #pragma unroll
        for (int i = 0; i < 4; ++i) {
            int row = wv * 16 + hi * 4 + i;
            Mpart[pb + row] = M_[i];
            Lpart[pb + row] = L_[i];
        }
    }
}

// ---------------------------------------------------------------------------
// Kernel 3: combine chunk partials. grid (S/64, B), block 256.
// ---------------------------------------------------------------------------
__global__ __launch_bounds__(256) void reduce_kernel(
    const float* __restrict__ Opart, const float* __restrict__ Mpart,
    const float* __restrict__ Lpart, float* __restrict__ out, int NC, int C)
{
    __shared__ float wexp[4][64];
    __shared__ float invL[64];
    const int qb = blockIdx.x, b = blockIdx.y, t = threadIdx.x;
    const int nact = (qb + C) / C;               // ceil((qb+1)/C)
    const size_t pb = ((size_t)b * 64 + qb) * NC * 64;
    if (t < 64) {
        float Mstar = -INFINITY;
        for (int c = 0; c < nact; ++c) Mstar = fmaxf(Mstar, Mpart[pb + c * 64 + t]);
        float Ls = 0.f;
        for (int c = 0; c < nact; ++c) {
            float wc = __expf(Mpart[pb + c * 64 + t] - Mstar);
            wexp[c][t] = wc;
            Ls += wc * Lpart[pb + c * 64 + t];
        }
        invL[t] = 1.f / Ls;
    }
    __syncthreads();
    #pragma unroll
    for (int rep = 0; rep < 8; ++rep) {
        int idx = rep * 256 + t;                 // 0..2047
        int row = idx >> 5, c4 = (idx & 31) * 4;
        float ox = 0.f, oy = 0.f, oz = 0.f, ow = 0.f;
        for (int c = 0; c < nact; ++c) {
            float wc = wexp[c][row];
            float4 v = *(const float4*)(Opart + (pb + (size_t)c * 64 + row) * 128 + c4);
            ox += wc * v.x; oy += wc * v.y; oz += wc * v.z; ow += wc * v.w;
        }
        float il = invL[row];
        float4 o = make_float4(ox * il, oy * il, oz * il, ow * il);
        *(float4*)(out + ((size_t)b * Ss + qb * 64 + row) * 128 + c4) = o;
    }
}

extern "C" void kernel_launch(void* const* d_in, const int* in_sizes, int n_in,
                              void* d_out, int out_size, void* d_ws, size_t ws_size,
                              hipStream_t stream) {
    (void)in_sizes; (void)n_in; (void)out_size;
    const float* embds = (const float*)d_in[0];
    const float* Wq = (const float*)d_in[1];
    const float* bq = (const float*)d_in[2];
    const float* Wk = (const float*)d_in[3];
    const float* bk = (const float*)d_in[4];
    const float* Wv = (const float*)d_in[5];
    const float* bv = (const float*)d_in[6];

    char* ws = (char*)d_ws;
    size_t off = 0;
    bf16* Qb = (bf16*)(ws + off); off += (size_t)Mrows * Hh * 2;
    bf16* Kb = (bf16*)(ws + off); off += (size_t)Mrows * Hh * 2;
    bf16* Vb = (bf16*)(ws + off); off += (size_t)Mrows * Hh * 2;
    bf16* Wt = (bf16*)(ws + off); off += (size_t)3 * Hh * Ee * 2;
    bf16* Biasb = (bf16*)(ws + off); off += 1024;

    int NC = 4;
    {
        auto need = [&](int nc) -> size_t {
            return off + (size_t)Bb * 64 * nc * 64 * 128 * 4
                       + (size_t)Bb * 64 * nc * 64 * 4 * 2;
        };
        if (need(NC) > ws_size) NC = 2;
        if (need(NC) > ws_size) NC = 1;
    }
    const int C = 64 / NC;
    float* Opart = (float*)(ws + off);
    size_t osz = (size_t)Bb * 64 * NC * 64 * 128 * 4;
    float* Mp = (float*)(ws + off + osz);
    float* Lp = Mp + (size_t)Bb * 64 * NC * 64;

    wprep_kernel<<<dim3(Ee / 64, 3), 256, 0, stream>>>(Wq, Wk, Wv, bq, bk, bv, Wt, Biasb);
    proj_kernel<<<dim3(Mrows / 64), 256, 0, stream>>>(embds, Wt, Biasb, Qb, Kb, Vb);
    attn_kernel<<<dim3(Ss / 64, Bb, NC), 256, 0, stream>>>(Qb, Kb, Vb, Opart, Mp, Lp, NC, C);
    reduce_kernel<<<dim3(Ss / 64, Bb), 256, 0, stream>>>(Opart, Mp, Lp, (float*)d_out, NC, C);
}